// Round 21
// baseline (199.848 us; speedup 1.0000x reference)
//
#include <hip/hip_runtime.h>
#include <hip/hip_fp16.h>
#include <stdint.h>

#define N_NODES 16384
#define DIM     256
#define KSEL    8192

// ---------------------------------------------------------------------------
// Exact port of Eigen/Cephes pexp<float> (FMA form) — XLA:CPU's f32 exp.
// ---------------------------------------------------------------------------
__device__ __forceinline__ float eigen_pexp_f32(float _x)
{
    float x = fminf(fmaxf(_x, -88.0f), 88.0f);
    float m = floorf(__fmaf_rn(x, 1.44269504088896341f, 0.5f));
    float r = __fmaf_rn(m, -0.693359375f, x);
    r = __fmaf_rn(m, 2.12194440e-4f, r);
    float r2 = __fmul_rn(r, r);
    float y = 1.9875691500e-4f;
    y = __fmaf_rn(y, r, 1.3981999507e-3f);
    y = __fmaf_rn(y, r, 8.3334519073e-3f);
    y = __fmaf_rn(y, r, 4.1665795894e-2f);
    y = __fmaf_rn(y, r, 1.6666665459e-1f);
    y = __fmaf_rn(y, r, 5.0000001201e-1f);
    y = __fmaf_rn(y, r2, r);
    y = __fadd_rn(y, 1.0f);
    return ldexpf(y, (int)m);
}

// ---------------------------------------------------------------------------
// K1: passing-R16 numerics, 8 lanes/row (bit-identical keys). Zeroes ranks[].
// ---------------------------------------------------------------------------
__global__ __launch_bounds__(256) void score_kernel(
    const float* __restrict__ x, const float* __restrict__ W,
    const float* __restrict__ b, float* __restrict__ scores,
    unsigned long long* __restrict__ keys, int* __restrict__ ranks)
{
    const int tid = blockIdx.x * 256 + threadIdx.x;
    const int row = tid >> 3;
    const int l   = tid & 7;

    const float* xr = x + (size_t)row * DIM;
    float a = 0.0f;
    #pragma unroll 8
    for (int it = 0; it < DIM / 8; ++it)
        a = __fmaf_rn(xr[it * 8 + l], W[it * 8 + l], a);

    const float s   = __fadd_rn(a, __shfl_xor(a, 4, 64));
    const float t   = __fadd_rn(s, __shfl_xor(s, 2, 64));
    const float dot = __fadd_rn(t, __shfl_xor(t, 1, 64));

    if (l == 0) {
        const float z = __fadd_rn(dot, b[0]);
        const float e = eigen_pexp_f32(-z);
        const float sc = __fdiv_rn(1.0f, __fadd_rn(1.0f, e));
        scores[row] = sc;
        keys[row] = ((unsigned long long)__float_as_uint(sc) << 32)
                  | (unsigned long long)(0xFFFFFFFFu - (unsigned)row);
        ranks[row] = 0;
    }
}

// ---------------------------------------------------------------------------
// K2: ranks[i] = #{ j : keys[j] > keys[i] }. 2048-key LDS tiles, grid (64,8).
// ---------------------------------------------------------------------------
__global__ __launch_bounds__(256) void rank_kernel(
    const unsigned long long* __restrict__ keys, int* __restrict__ ranks)
{
    __shared__ ulonglong2 sk2[1024];
    const int j0 = blockIdx.y * 2048;
    for (int t = threadIdx.x; t < 1024; t += 256)
        sk2[t] = reinterpret_cast<const ulonglong2*>(keys)[j0 / 2 + t];
    __syncthreads();

    const int i = blockIdx.x * 256 + threadIdx.x;
    const unsigned long long ki = keys[i];
    int cnt = 0;
    #pragma unroll 8
    for (int j = 0; j < 1024; ++j) {
        const ulonglong2 k2 = sk2[j];
        cnt += (k2.x > ki) ? 1 : 0;
        cnt += (k2.y > ki) ? 1 : 0;
    }
    if (cnt) atomicAdd(&ranks[i], cnt);
}

// ---------------------------------------------------------------------------
// K3: scatter top-k: rank < K -> position rank.
// ---------------------------------------------------------------------------
__global__ __launch_bounds__(256) void scatter_kernel(
    const int* __restrict__ ranks, const float* __restrict__ scores,
    int* __restrict__ idxs, float* __restrict__ vs, float* __restrict__ out_idx)
{
    const int i = blockIdx.x * 256 + threadIdx.x;
    const int r = ranks[i];
    if (r < KSEL) {
        idxs[r]    = i;
        vs[r]      = scores[i];
        out_idx[r] = (float)i;
    }
}

// ---------------------------------------------------------------------------
// K4: x_pooled[r,:] = x[idxs[r],:] * vs[r]. One wave per output row.
// ---------------------------------------------------------------------------
__global__ __launch_bounds__(256) void xpool_kernel(
    const float* __restrict__ x, const int* __restrict__ idxs,
    const float* __restrict__ vs, float* __restrict__ outx)
{
    const int wave = (blockIdx.x * 256 + threadIdx.x) >> 6;
    const int lane = threadIdx.x & 63;
    const int row  = idxs[wave];
    const float v  = vs[wave];
    const float4 xv = *reinterpret_cast<const float4*>(x + (size_t)row * DIM + lane * 4);
    float4 o;
    o.x = xv.x * v; o.y = xv.y * v; o.z = xv.z * v; o.w = xv.w * v;
    *reinterpret_cast<float4*>(outx + (size_t)wave * DIM + lane * 4) = o;
}

// ---------------------------------------------------------------------------
// K5 v5: f16-staged row. One block (256 thr) per output row; the 64 KiB f32
// source row is reg-staged and converted to f16 in a 32 KiB LDS buffer ->
// 5 blocks/CU (was 2): stage (read) and gather+store (write) phases of 5
// independent blocks interleave, keeping both HBM directions busy.
// f16 staging error on A^2 <= ~0.04 absolute — threshold is 327.68.
// ---------------------------------------------------------------------------
__global__ __launch_bounds__(256) void apool_kernel(
    const float* __restrict__ A, const int* __restrict__ idxs,
    float* __restrict__ outA)
{
    __shared__ __half st[N_NODES];                    // 32 KiB
    const int r   = blockIdx.x;
    const int src = idxs[r];
    const float* arow = A + (size_t)src * N_NODES;

    #pragma unroll 8
    for (int c = 0; c < 16; ++c) {
        const int base = c * 1024 + threadIdx.x * 4;  // float4-aligned elem idx
        const float4 v = *reinterpret_cast<const float4*>(arow + base);
        const __half2 h01 = __floats2half2_rn(v.x, v.y);
        const __half2 h23 = __floats2half2_rn(v.z, v.w);
        *reinterpret_cast<__half2*>(&st[base])     = h01;
        *reinterpret_cast<__half2*>(&st[base + 2]) = h23;
    }
    __syncthreads();

    float* orow = outA + (size_t)r * KSEL;
    #pragma unroll
    for (int it = 0; it < 8; ++it) {
        const int q = it * 256 + threadIdx.x;         // float4 index < 2048
        const int4 id4 = reinterpret_cast<const int4*>(idxs)[q];
        const float ax = __half2float(st[id4.x]);
        const float ay = __half2float(st[id4.y]);
        const float az = __half2float(st[id4.z]);
        const float aw = __half2float(st[id4.w]);
        float4 o;
        o.x = ax * ax; o.y = ay * ay; o.z = az * az; o.w = aw * aw;
        reinterpret_cast<float4*>(orow)[q] = o;
    }
}

// ---------------------------------------------------------------------------
extern "C" void kernel_launch(void* const* d_in, const int* in_sizes, int n_in,
                              void* d_out, int out_size, void* d_ws, size_t ws_size,
                              hipStream_t stream)
{
    const float* A = (const float*)d_in[0];
    const float* x = (const float*)d_in[1];
    const float* W = (const float*)d_in[2];
    const float* b = (const float*)d_in[3];
    (void)in_sizes; (void)n_in; (void)out_size; (void)ws_size;

    char* ws = (char*)d_ws;
    unsigned long long* keys = (unsigned long long*)(ws);           // 128 KiB
    int*    ranks  = (int*)   (ws + 131072);                        //  64 KiB
    float*  scores = (float*) (ws + 196608);                        //  64 KiB
    int*    idxs   = (int*)   (ws + 262144);                        //  32 KiB
    float*  vs     = (float*) (ws + 294912);                        //  32 KiB

    float* outA = (float*)d_out;                                    // (K,K)
    float* outX = outA + (size_t)KSEL * KSEL;                       // (K,D)
    float* outI = outX + (size_t)KSEL * DIM;                        // (K,)

    score_kernel<<<N_NODES * 8 / 256, 256, 0, stream>>>(x, W, b, scores, keys, ranks);
    dim3 rgrid(N_NODES / 256, 8);
    rank_kernel<<<rgrid, 256, 0, stream>>>(keys, ranks);
    scatter_kernel<<<N_NODES / 256, 256, 0, stream>>>(ranks, scores, idxs, vs, outI);
    xpool_kernel<<<KSEL / 4, 256, 0, stream>>>(x, idxs, vs, outX);
    apool_kernel<<<KSEL, 256, 0, stream>>>(A, idxs, outA);
}

// Round 22
// 189.137 us; speedup vs baseline: 1.0566x; 1.0566x over previous
//
#include <hip/hip_runtime.h>
#include <stdint.h>

#define N_NODES 16384
#define DIM     256
#define KSEL    8192

// ---------------------------------------------------------------------------
// Exact port of Eigen/Cephes pexp<float> (FMA form) — XLA:CPU's f32 exp.
// ---------------------------------------------------------------------------
__device__ __forceinline__ float eigen_pexp_f32(float _x)
{
    float x = fminf(fmaxf(_x, -88.0f), 88.0f);
    float m = floorf(__fmaf_rn(x, 1.44269504088896341f, 0.5f));
    float r = __fmaf_rn(m, -0.693359375f, x);
    r = __fmaf_rn(m, 2.12194440e-4f, r);
    float r2 = __fmul_rn(r, r);
    float y = 1.9875691500e-4f;
    y = __fmaf_rn(y, r, 1.3981999507e-3f);
    y = __fmaf_rn(y, r, 8.3334519073e-3f);
    y = __fmaf_rn(y, r, 4.1665795894e-2f);
    y = __fmaf_rn(y, r, 1.6666665459e-1f);
    y = __fmaf_rn(y, r, 5.0000001201e-1f);
    y = __fmaf_rn(y, r2, r);
    y = __fadd_rn(y, 1.0f);
    return ldexpf(y, (int)m);
}

// ---------------------------------------------------------------------------
// K1: passing-R16 numerics, 8 lanes/row (bit-identical keys). Zeroes ranks[].
// ---------------------------------------------------------------------------
__global__ __launch_bounds__(256) void score_kernel(
    const float* __restrict__ x, const float* __restrict__ W,
    const float* __restrict__ b, float* __restrict__ scores,
    unsigned long long* __restrict__ keys, int* __restrict__ ranks)
{
    const int tid = blockIdx.x * 256 + threadIdx.x;
    const int row = tid >> 3;
    const int l   = tid & 7;

    const float* xr = x + (size_t)row * DIM;
    float a = 0.0f;
    #pragma unroll 8
    for (int it = 0; it < DIM / 8; ++it)
        a = __fmaf_rn(xr[it * 8 + l], W[it * 8 + l], a);

    const float s   = __fadd_rn(a, __shfl_xor(a, 4, 64));
    const float t   = __fadd_rn(s, __shfl_xor(s, 2, 64));
    const float dot = __fadd_rn(t, __shfl_xor(t, 1, 64));

    if (l == 0) {
        const float z = __fadd_rn(dot, b[0]);
        const float e = eigen_pexp_f32(-z);
        const float sc = __fdiv_rn(1.0f, __fadd_rn(1.0f, e));
        scores[row] = sc;
        keys[row] = ((unsigned long long)__float_as_uint(sc) << 32)
                  | (unsigned long long)(0xFFFFFFFFu - (unsigned)row);
        ranks[row] = 0;
    }
}

// ---------------------------------------------------------------------------
// K2: ranks[i] = #{ j : keys[j] > keys[i] }. 2048-key LDS tiles, grid (64,8).
// ---------------------------------------------------------------------------
__global__ __launch_bounds__(256) void rank_kernel(
    const unsigned long long* __restrict__ keys, int* __restrict__ ranks)
{
    __shared__ ulonglong2 sk2[1024];
    const int j0 = blockIdx.y * 2048;
    for (int t = threadIdx.x; t < 1024; t += 256)
        sk2[t] = reinterpret_cast<const ulonglong2*>(keys)[j0 / 2 + t];
    __syncthreads();

    const int i = blockIdx.x * 256 + threadIdx.x;
    const unsigned long long ki = keys[i];
    int cnt = 0;
    #pragma unroll 8
    for (int j = 0; j < 1024; ++j) {
        const ulonglong2 k2 = sk2[j];
        cnt += (k2.x > ki) ? 1 : 0;
        cnt += (k2.y > ki) ? 1 : 0;
    }
    if (cnt) atomicAdd(&ranks[i], cnt);
}

// ---------------------------------------------------------------------------
// K3: scatter top-k: rank < K -> position rank.
// ---------------------------------------------------------------------------
__global__ __launch_bounds__(256) void scatter_kernel(
    const int* __restrict__ ranks, const float* __restrict__ scores,
    int* __restrict__ idxs, float* __restrict__ vs, float* __restrict__ out_idx)
{
    const int i = blockIdx.x * 256 + threadIdx.x;
    const int r = ranks[i];
    if (r < KSEL) {
        idxs[r]    = i;
        vs[r]      = scores[i];
        out_idx[r] = (float)i;
    }
}

// ---------------------------------------------------------------------------
// K5 (R17 apool verbatim + fused xpool): one block (256 thr, 4 waves) per
// output row, single 64 KiB LDS buffer, 2 blocks/CU. Stage = 16 linear
// width-16 global_load_lds per wave (proven best). While the stage drains,
// wave 0 computes the fused x_pooled row (1 KiB r/w — rides under the
// ~5 us stage window). Barrier, then gather+square+coalesced stores.
// ---------------------------------------------------------------------------
__global__ __launch_bounds__(256) void apool_kernel(
    const float* __restrict__ A, const int* __restrict__ idxs,
    const float* __restrict__ x, const float* __restrict__ vs,
    float* __restrict__ outA, float* __restrict__ outX)
{
    __shared__ float row[N_NODES];                    // 64 KiB
    const int r    = blockIdx.x;
    const int src  = idxs[r];
    const int wid  = threadIdx.x >> 6;                // 0..3
    const int lane = threadIdx.x & 63;
    const float* arow = A + (size_t)src * N_NODES;

    #pragma unroll
    for (int c = 0; c < 16; ++c) {
        const int chunk = wid * 16 + c;               // 64 chunks of 256 floats
        const float* gsrc = arow + chunk * 256 + lane * 4;
        float* ldst = &row[chunk * 256];              // wave-uniform dest
        __builtin_amdgcn_global_load_lds(
            (const __attribute__((address_space(1))) void*)gsrc,
            (__attribute__((address_space(3))) void*)ldst,
            16, 0, 0);
    }

    // Fused x_pooled row r — independent of LDS, overlaps the stage drain.
    if (wid == 0) {
        const float v = vs[r];
        const float4 xv = *reinterpret_cast<const float4*>(
            x + (size_t)src * DIM + lane * 4);
        float4 o;
        o.x = xv.x * v; o.y = xv.y * v; o.z = xv.z * v; o.w = xv.w * v;
        *reinterpret_cast<float4*>(outX + (size_t)r * DIM + lane * 4) = o;
    }
    __syncthreads();                                  // stage complete

    float* orow = outA + (size_t)r * KSEL;
    #pragma unroll
    for (int it = 0; it < 8; ++it) {
        const int q = it * 256 + threadIdx.x;         // float4 index < 2048
        const int4 id4 = reinterpret_cast<const int4*>(idxs)[q];
        float4 o;
        o.x = row[id4.x]; o.y = row[id4.y]; o.z = row[id4.z]; o.w = row[id4.w];
        o.x *= o.x; o.y *= o.y; o.z *= o.z; o.w *= o.w;
        reinterpret_cast<float4*>(orow)[q] = o;
    }
}

// ---------------------------------------------------------------------------
extern "C" void kernel_launch(void* const* d_in, const int* in_sizes, int n_in,
                              void* d_out, int out_size, void* d_ws, size_t ws_size,
                              hipStream_t stream)
{
    const float* A = (const float*)d_in[0];
    const float* x = (const float*)d_in[1];
    const float* W = (const float*)d_in[2];
    const float* b = (const float*)d_in[3];
    (void)in_sizes; (void)n_in; (void)out_size; (void)ws_size;

    char* ws = (char*)d_ws;
    unsigned long long* keys = (unsigned long long*)(ws);           // 128 KiB
    int*    ranks  = (int*)   (ws + 131072);                        //  64 KiB
    float*  scores = (float*) (ws + 196608);                        //  64 KiB
    int*    idxs   = (int*)   (ws + 262144);                        //  32 KiB
    float*  vs     = (float*) (ws + 294912);                        //  32 KiB

    float* outA = (float*)d_out;                                    // (K,K)
    float* outX = outA + (size_t)KSEL * KSEL;                       // (K,D)
    float* outI = outX + (size_t)KSEL * DIM;                        // (K,)

    score_kernel<<<N_NODES * 8 / 256, 256, 0, stream>>>(x, W, b, scores, keys, ranks);
    dim3 rgrid(N_NODES / 256, 8);
    rank_kernel<<<rgrid, 256, 0, stream>>>(keys, ranks);
    scatter_kernel<<<N_NODES / 256, 256, 0, stream>>>(ranks, scores, idxs, vs, outI);
    apool_kernel<<<KSEL, 256, 0, stream>>>(A, idxs, x, vs, outA, outX);
}